// Round 1
// baseline (3402.477 us; speedup 1.0000x reference)
//
#include <hip/hip_runtime.h>
#include <hip/hip_bf16.h>

// Sizes (fixed by the reference)
#define NN 131072
#define EE 1048576
#define IN_F 74
#define HH 128
#define LL 3

// ---------------- init: h = nf @ W_init  ([N x 74] @ [74 x 128]) ----------------
__global__ __launch_bounds__(256) void k_init_gemm(
    const float* __restrict__ nf, const float* __restrict__ Wi,
    float* __restrict__ h, int n)
{
    int node = blockIdx.x * 2 + (threadIdx.x >> 7);
    int c = threadIdx.x & 127;
    if (node >= n) return;
    const float* row = nf + (long)node * IN_F;
    float s = 0.f;
#pragma unroll
    for (int k = 0; k < IN_F; ++k)
        s += row[k] * Wi[k * HH + c];
    h[(long)node * HH + c] = s;
}

// ---------------- scatter: agg[dst] += h[src], 1 thread per (edge,col) ----------------
__global__ __launch_bounds__(256) void k_scatter(
    const int* __restrict__ src, const int* __restrict__ dst,
    const float* __restrict__ h, float* __restrict__ agg)
{
    long idx = (long)blockIdx.x * blockDim.x + threadIdx.x;
    int e = (int)(idx >> 7);
    int c = (int)(idx & 127);
    int s = src[e];
    int d = dst[e];
    atomicAdd(&agg[(long)d * HH + c], h[(long)s * HH + c]);
}

// ---------------- tiled f32 GEMM: C[rows x M] = act(A[rows x 128] @ W[M x 128]^T + b) ----------------
// BM=128, BN=64, BK=32, 256 threads, 8x4 register tile per thread.
template <bool RELU>
__global__ __launch_bounds__(256) void k_gemm(
    const float* __restrict__ A, const float* __restrict__ W,
    const float* __restrict__ bias, float* __restrict__ C,
    int rows, int M)
{
    __shared__ float As[32][132]; // [k][m], padded
    __shared__ float Bs[32][68];  // [k][n], padded

    int row0 = blockIdx.x * 128;
    int col0 = blockIdx.y * 64;
    int tid = threadIdx.x;
    int tx = tid & 15;  // m group
    int ty = tid >> 4;  // n group
    int tm0 = tx * 8, tn0 = ty * 4;

    float acc[8][4] = {};

    for (int k0 = 0; k0 < 128; k0 += 32) {
        // Load A tile (128 x 32): 4 passes of 32 rows x 8 float4
        {
            int r = tid >> 3;  // 0..31
            int c4 = tid & 7;  // 0..7
#pragma unroll
            for (int p = 0; p < 4; ++p) {
                int rr = r + p * 32;
                int grow = row0 + rr;
                float4 v = make_float4(0.f, 0.f, 0.f, 0.f);
                if (grow < rows)
                    v = *reinterpret_cast<const float4*>(&A[(long)grow * 128 + k0 + c4 * 4]);
                As[c4 * 4 + 0][rr] = v.x;
                As[c4 * 4 + 1][rr] = v.y;
                As[c4 * 4 + 2][rr] = v.z;
                As[c4 * 4 + 3][rr] = v.w;
            }
        }
        // Load W tile (64 x 32): 2 passes of 32 rows x 8 float4
        {
            int r = tid >> 3;
            int c4 = tid & 7;
#pragma unroll
            for (int p = 0; p < 2; ++p) {
                int rr = r + p * 32;
                int wrow = col0 + rr;
                float4 v = *reinterpret_cast<const float4*>(&W[(long)wrow * 128 + k0 + c4 * 4]);
                Bs[c4 * 4 + 0][rr] = v.x;
                Bs[c4 * 4 + 1][rr] = v.y;
                Bs[c4 * 4 + 2][rr] = v.z;
                Bs[c4 * 4 + 3][rr] = v.w;
            }
        }
        __syncthreads();
#pragma unroll
        for (int k = 0; k < 32; ++k) {
            float4 a0 = *reinterpret_cast<const float4*>(&As[k][tm0]);
            float4 a1 = *reinterpret_cast<const float4*>(&As[k][tm0 + 4]);
            float4 b = *reinterpret_cast<const float4*>(&Bs[k][tn0]);
            float a[8] = {a0.x, a0.y, a0.z, a0.w, a1.x, a1.y, a1.z, a1.w};
            float bb[4] = {b.x, b.y, b.z, b.w};
#pragma unroll
            for (int i = 0; i < 8; ++i)
#pragma unroll
                for (int j = 0; j < 4; ++j)
                    acc[i][j] += a[i] * bb[j];
        }
        __syncthreads();
    }

#pragma unroll
    for (int i = 0; i < 8; ++i) {
        int grow = row0 + tm0 + i;
        if (grow >= rows) break;
#pragma unroll
        for (int j = 0; j < 4; ++j) {
            float v = acc[i][j] + bias[col0 + tn0 + j];
            if (RELU) v = fmaxf(v, 0.f);
            C[(long)grow * M + col0 + tn0 + j] = v;
        }
    }
}

// ---------------- GRU gates (elementwise) ----------------
__global__ __launch_bounds__(256) void k_gates(
    const float* __restrict__ gi, const float* __restrict__ gh,
    float* __restrict__ h, int nrows)
{
    long idx = (long)blockIdx.x * blockDim.x + threadIdx.x;
    if (idx >= (long)nrows * 128) return;
    int n = (int)(idx >> 7);
    int j = (int)(idx & 127);
    const float* gir = gi + (long)n * 384;
    const float* ghr = gh + (long)n * 384;
    float ir = gir[j], iz = gir[128 + j], in_ = gir[256 + j];
    float hr = ghr[j], hz = ghr[128 + j], hn = ghr[256 + j];
    float r = 1.f / (1.f + __expf(-(ir + hr)));
    float z = 1.f / (1.f + __expf(-(iz + hz)));
    float nn = tanhf(in_ + r * hn);
    float hv = h[idx];
    h[idx] = (1.f - z) * nn + z * hv;
}

extern "C" void kernel_launch(void* const* d_in, const int* in_sizes, int n_in,
                              void* d_out, int out_size, void* d_ws, size_t ws_size,
                              hipStream_t stream)
{
    const float* nf    = (const float*)d_in[0];  // [N][74]
    const int*   src   = (const int*)d_in[1];    // [E]
    const int*   dst   = (const int*)d_in[2];    // [E]
    const float* W_init = (const float*)d_in[3]; // [74][128]
    const float* lin_W = (const float*)d_in[4];  // [3][128][128]
    const float* lin_b = (const float*)d_in[5];  // [3][128]
    const float* Wih   = (const float*)d_in[6];  // [3][384][128]
    const float* Whh   = (const float*)d_in[7];  // [3][384][128]
    const float* bih   = (const float*)d_in[8];  // [3][384]
    const float* bhh   = (const float*)d_in[9];  // [3][384]

    const int N = NN;
    const int E = EE;

    float* h = (float*)d_out;  // h lives in d_out throughout (N x 128 f32)

    // ws layout: [0, 64MB) agg (reused as gi/gh chunk buffers after x-GEMM),
    //            [64MB, 128MB) x
    char* ws = (char*)d_ws;
    float* agg = (float*)ws;
    float* xbuf = (float*)(ws + (size_t)N * 128 * 4);
    float* gi_buf = (float*)ws;                             // reuse agg region
    float* gh_buf = (float*)(ws + (size_t)N * 128 * 4 / 2); // agg + 32MB

    const int NC = 16384;            // node chunk for gi/gh (8 chunks exactly)
    const int NCHUNK = N / NC;

    // ---- init transform ----
    k_init_gemm<<<N / 2, 256, 0, stream>>>(nf, W_init, h, N);

    for (int l = 0; l < LL; ++l) {
        const float* lW = lin_W + (size_t)l * 128 * 128;
        const float* lb = lin_b + (size_t)l * 128;
        const float* wih = Wih + (size_t)l * 384 * 128;
        const float* whh = Whh + (size_t)l * 384 * 128;
        const float* bi = bih + (size_t)l * 384;
        const float* bh = bhh + (size_t)l * 384;

        // agg = segment_sum(h[src], dst)
        hipMemsetAsync(agg, 0, (size_t)N * 128 * 4, stream);
        {
            long total = (long)E * 128;
            int blocks = (int)(total / 256);
            k_scatter<<<blocks, 256, 0, stream>>>(src, dst, h, agg);
        }

        // x = relu(agg @ lW^T + lb)
        {
            dim3 grid(N / 128, 128 / 64);
            k_gemm<true><<<grid, 256, 0, stream>>>(agg, lW, lb, xbuf, N, 128);
        }

        // GRU per node-chunk: gi = x @ Wih^T + bih ; gh = h @ Whh^T + bhh ; gates
        for (int c = 0; c < NCHUNK; ++c) {
            int n0 = c * NC;
            const float* xA = xbuf + (long)n0 * 128;
            float* hA = h + (long)n0 * 128;
            dim3 grid(NC / 128, 384 / 64);
            k_gemm<false><<<grid, 256, 0, stream>>>(xA, wih, bi, gi_buf, NC, 384);
            k_gemm<false><<<grid, 256, 0, stream>>>(hA, whh, bh, gh_buf, NC, 384);
            k_gates<<<(NC * 128) / 256, 256, 0, stream>>>(gi_buf, gh_buf, hA, NC);
        }
    }
}